// Round 1
// 255.080 us; speedup vs baseline: 1.2127x; 1.2127x over previous
//
#include <hip/hip_runtime.h>

#define B_ 4
#define N_ 1000000
#define K_ 2048
#define P_ 1000
#define CAP_ 8192
#define THR_ 0.7f
#define NF4_ 500000     // float4 count per batch of (N,2) float array
#define META_STRIDE 32  // u32 per batch -> 128 B: counters on separate cache lines
#define TILE_ 512       // rank tile (candidates per tile-chunk)
#define NCH_ (CAP_ / TILE_)  // 16 tile chunks max

// ---- workspace layout (bytes) ----
// hist   : B * 65536 * 4 = 1,048,576
// meta   : 1024  (per batch at b*META_STRIDE: [0]=threshold bucket, [1]=candidate count)
// coarse : B * 256 * 4 = 4,096
// cand   : B * CAP * 8   = 262,144   (uint2: key, idx)
// topidx : B * K * 4     = 32,768    (unused after scatter fusion; layout kept)
// boxes  : B * K * 16    = 131,072
// mask   : B * K * 32 * 8 = 2,097,152
//   NOTE: partial-rank array (B * NCH_ * CAP_ * 4 = 2,097,152) ALIASES mask:
//   rank_kernel writes it, scatter_kernel consumes it, THEN mask_kernel overwrites.
#define OFF_HIST 0
#define OFF_META 1048576
#define OFF_COARSE (OFF_META + 1024)
#define OFF_CAND (OFF_COARSE + 4096)
#define OFF_TOPI (OFF_CAND + 262144)
#define OFF_BOX  (OFF_TOPI + 32768)
#define OFF_MASK (OFF_BOX + 131072)

__device__ __forceinline__ unsigned fkey(float f) {
  unsigned u = __float_as_uint(f);
  return (u & 0x80000000u) ? ~u : (u | 0x80000000u);
}

__device__ __forceinline__ unsigned long long readlane64(unsigned long long v, int l) {
  unsigned lo = (unsigned)__builtin_amdgcn_readlane((int)(unsigned)(v & 0xffffffffull), l);
  unsigned hi = (unsigned)__builtin_amdgcn_readlane((int)(unsigned)(v >> 32), l);
  return ((unsigned long long)hi << 32) | (unsigned long long)lo;
}

#define PIN16(k) asm volatile("" : "+v"(k[0]), "+v"(k[1]), "+v"(k[2]), "+v"(k[3]), \
                                   "+v"(k[4]), "+v"(k[5]), "+v"(k[6]), "+v"(k[7]), \
                                   "+v"(k[8]), "+v"(k[9]), "+v"(k[10]), "+v"(k[11]), \
                                   "+v"(k[12]), "+v"(k[13]), "+v"(k[14]), "+v"(k[15]))

// ---- K1: LDS-privatized histogram of top-16 bits of monotonic key ----
__global__ void __launch_bounds__(1024) hist_kernel(const float4* __restrict__ probs4,
                                                    unsigned* __restrict__ hist) {
  int b = blockIdx.y;
  __shared__ unsigned h[32768];
  for (int i = threadIdx.x; i < 32768; i += 1024) h[i] = 0u;
  __syncthreads();
  const float4* p4 = probs4 + (size_t)b * NF4_;
  int base = blockIdx.x * 8192;
  float4 v[8];
#pragma unroll
  for (int c = 0; c < 8; ++c) {
    int i4 = base + c * 1024 + threadIdx.x;
    v[c] = (i4 < NF4_) ? p4[i4] : make_float4(0.f, 0.f, 0.f, 0.f);
  }
  unsigned k[16];
#pragma unroll
  for (int c = 0; c < 8; ++c) { k[2 * c] = fkey(v[c].y) >> 16; k[2 * c + 1] = fkey(v[c].w) >> 16; }
  PIN16(k);
#pragma unroll
  for (int c = 0; c < 8; ++c) {
    int i4 = base + c * 1024 + threadIdx.x;
    if (i4 < NF4_) {
      unsigned b0 = k[2 * c], b1 = k[2 * c + 1];
      atomicAdd(&h[b0 >> 1], 1u << ((b0 & 1u) << 4));
      atomicAdd(&h[b1 >> 1], 1u << ((b1 & 1u) << 4));
    }
  }
  __syncthreads();
  unsigned* g = hist + ((size_t)b << 16);
  for (int w = threadIdx.x; w < 32768; w += 1024) {
    unsigned x = h[w];
    if (x) {
      unsigned c0 = x & 0xFFFFu, c1 = x >> 16;
      if (c0) atomicAdd(&g[2 * w], c0);
      if (c1) atomicAdd(&g[2 * w + 1], c1);
    }
  }
}

// ---- K2a: coarse sums — one wave per 256-bucket group, coalesced + shfl-reduce ----
__global__ void __launch_bounds__(64) coarse_kernel(const unsigned* __restrict__ hist,
                                                    unsigned* __restrict__ coarse) {
  int b = blockIdx.y, g = blockIdx.x, lane = threadIdx.x;
  const uint4* h4 = (const uint4*)(hist + (((size_t)b) << 16) + ((size_t)g << 8));
  uint4 v = h4[lane];
  unsigned s = v.x + v.y + v.z + v.w;
#pragma unroll
  for (int off = 32; off >= 1; off >>= 1) s += __shfl_xor(s, off, 64);
  if (lane == 0) coarse[b * 256 + g] = s;
}

// ---- K2b: find smallest bucket cb with count(bucket >= cb) >= K ----
__global__ void select_kernel(const unsigned* __restrict__ hist, const unsigned* __restrict__ coarse,
                              unsigned* __restrict__ meta) {
  int b = blockIdx.x, t = threadIdx.x;  // 256 threads
  __shared__ unsigned suf[256];
  __shared__ int tc_s;
  __shared__ unsigned above_s;
  const unsigned* g = hist + ((size_t)b << 16);
  suf[t] = coarse[b * 256 + t];
  __syncthreads();
  for (int off = 1; off < 256; off <<= 1) {
    unsigned add = (t + off < 256) ? suf[t + off] : 0u;
    __syncthreads();
    suf[t] += add;
    __syncthreads();
  }
  unsigned nxt = (t < 255) ? suf[t + 1] : 0u;
  if (suf[t] >= K_ && (t == 255 || nxt < K_)) { tc_s = t; above_s = nxt; }
  __syncthreads();
  int tc = tc_s;
  unsigned above = above_s;
  unsigned bs = g[tc * 256 + t];
  __syncthreads();
  suf[t] = bs;
  __syncthreads();
  for (int off = 1; off < 256; off <<= 1) {
    unsigned add = (t + off < 256) ? suf[t + off] : 0u;
    __syncthreads();
    suf[t] += add;
    __syncthreads();
  }
  unsigned nxt2 = (t < 255) ? suf[t + 1] : 0u;
  if (above + suf[t] >= K_ && (t == 255 || above + nxt2 < K_))
    meta[b * META_STRIDE + 0] = (unsigned)(tc * 256 + t);
}

// ---- K3: compact candidates (bucket >= cb), LDS-buffered, 1 global atomic/block ----
__global__ void __launch_bounds__(256) compact_kernel(const float4* __restrict__ probs4,
                                                      unsigned* __restrict__ meta,
                                                      uint2* __restrict__ cand) {
  int b = blockIdx.y;
  __shared__ unsigned lcnt, gbase_s;
  __shared__ uint2 buf[4096];
  if (threadIdx.x == 0) lcnt = 0u;
  __syncthreads();
  unsigned cb = meta[b * META_STRIDE + 0];
  const float4* p4 = probs4 + (size_t)b * NF4_;
  int base = blockIdx.x * 2048;
  int lane = threadIdx.x & 63;
  float4 v[8];
#pragma unroll
  for (int c = 0; c < 8; ++c) {
    int i4 = base + c * 256 + threadIdx.x;
    v[c] = (i4 < NF4_) ? p4[i4] : make_float4(0.f, 0.f, 0.f, 0.f);
  }
  unsigned k[16];
#pragma unroll
  for (int c = 0; c < 8; ++c) { k[2 * c] = fkey(v[c].y); k[2 * c + 1] = fkey(v[c].w); }
  PIN16(k);
#pragma unroll
  for (int c = 0; c < 8; ++c) {
#pragma unroll
    for (int s = 0; s < 2; ++s) {
      int i4 = base + c * 256 + threadIdx.x;
      unsigned key = k[2 * c + s];
      bool pass = (i4 < NF4_) && ((key >> 16) >= cb);
      unsigned long long m = __ballot(pass);
      if (m) {
        int leader = __ffsll(m) - 1;
        unsigned wbase = 0;
        if (lane == leader) wbase = atomicAdd(&lcnt, (unsigned)__popcll(m));
        wbase = __shfl(wbase, leader, 64);
        if (pass) {
          unsigned pos = wbase + (unsigned)__popcll(m & ((1ull << lane) - 1ull));
          buf[pos] = make_uint2(key, (unsigned)(2 * i4 + s));
        }
      }
    }
  }
  __syncthreads();
  unsigned cnt = lcnt;
  if (threadIdx.x == 0) gbase_s = atomicAdd(&meta[b * META_STRIDE + 1], cnt);
  __syncthreads();
  unsigned gbase = gbase_s;
  for (unsigned i = threadIdx.x; i < cnt; i += 256) {
    unsigned pos = gbase + i;
    if (pos < CAP_) cand[(size_t)b * CAP_ + pos] = buf[i];
  }
}

// ---- K4: exact rank by counting, 2D-split (ci-chunk x tile-chunk) for occupancy ----
// Each block ranks 256 candidates against one TILE_-candidate tile; partial ranks
// go to partial[b][tile_chunk][ci] (no atomics, no zero-init needed: scatter sums
// exactly the chunks with tile_base < M, all of which were written).
__global__ void __launch_bounds__(256) rank_kernel(const uint2* __restrict__ cand,
                                                   const unsigned* __restrict__ meta,
                                                   unsigned* __restrict__ partial) {
  int b = blockIdx.z;
  unsigned M = meta[b * META_STRIDE + 1];
  if (M > CAP_) M = CAP_;
  unsigned tb = blockIdx.y * TILE_;
  if (tb >= M) return;
  if ((unsigned)(blockIdx.x * 256) >= M) return;
  __shared__ __align__(16) uint2 tile[TILE_];
  unsigned n = M - tb;
  if (n > TILE_) n = TILE_;
  for (unsigned t = threadIdx.x; t < n; t += 256) tile[t] = cand[(size_t)b * CAP_ + tb + t];
  int ci = blockIdx.x * 256 + threadIdx.x;
  bool act = ci < (int)M;
  uint2 me = make_uint2(0u, 0u);
  if (act) me = cand[(size_t)b * CAP_ + ci];
  unsigned long long my = ((unsigned long long)me.x << 32) | (unsigned long long)(unsigned)(~me.y);
  __syncthreads();
  if (act) {
    unsigned rank = 0;
    unsigned n2 = n >> 1;
    const uint4* t4 = (const uint4*)tile;
    for (unsigned j = 0; j < n2; ++j) {
      uint4 v = t4[j];
      unsigned long long c0 = ((unsigned long long)v.x << 32) | (unsigned long long)(unsigned)(~v.y);
      unsigned long long c1 = ((unsigned long long)v.z << 32) | (unsigned long long)(unsigned)(~v.w);
      rank += (unsigned)(c0 > my) + (unsigned)(c1 > my);
    }
    if (n & 1) {
      uint2 v = tile[n - 1];
      unsigned long long c0 = ((unsigned long long)v.x << 32) | (unsigned long long)(unsigned)(~v.y);
      rank += (unsigned)(c0 > my);
    }
    partial[((size_t)b * NCH_ + blockIdx.y) * CAP_ + ci] = rank;
  }
}

// ---- K5: sum partial ranks, gather anchors/deltas, decode boxes, clip (fused) ----
__global__ void __launch_bounds__(256) scatter_kernel(const uint2* __restrict__ cand,
                                                      const unsigned* __restrict__ meta,
                                                      const unsigned* __restrict__ partial,
                                                      const float4* __restrict__ bbox,
                                                      const float4* __restrict__ anch,
                                                      float4* __restrict__ boxes) {
  int b = blockIdx.y;
  unsigned M = meta[b * META_STRIDE + 1];
  if (M > CAP_) M = CAP_;
  unsigned ci = blockIdx.x * 256 + threadIdx.x;
  if (ci >= M) return;
  unsigned nch = (M + TILE_ - 1) / TILE_;
  const unsigned* pp = partial + (size_t)b * NCH_ * CAP_ + ci;
  unsigned rank = 0;
  for (unsigned c = 0; c < nch; ++c) rank += pp[(size_t)c * CAP_];
  if (rank >= K_) return;
  unsigned idx = cand[(size_t)b * CAP_ + ci].y;
  size_t base = (size_t)b * N_ + idx;
  float4 a = anch[base];
  float4 d = bbox[base];
  float d0 = d.x * 0.1f, d1 = d.y * 0.1f, d2 = d.z * 0.2f, d3 = d.w * 0.2f;
  float h = a.z - a.x, w = a.w - a.y;
  float cy = (a.x + 0.5f * h) + d0 * h;
  float cx = (a.y + 0.5f * w) + d1 * w;
  float h2 = h * expf(d2);
  float w2 = w * expf(d3);
  float y1 = cy - 0.5f * h2, x1 = cx - 0.5f * w2;
  float y2 = cy + 0.5f * h2, x2 = cx + 0.5f * w2;
  y1 = fminf(fmaxf(y1, 0.f), 1.f);
  x1 = fminf(fmaxf(x1, 0.f), 1.f);
  y2 = fminf(fmaxf(y2, 0.f), 1.f);
  x2 = fminf(fmaxf(x2, 0.f), 1.f);
  boxes[(b << 11) + rank] = make_float4(y1, x1, y2, x2);
}

// ---- K6: IoU suppression bitmask (upper-triangular word-blocks only) ----
__global__ void mask_kernel(const float4* __restrict__ boxes, unsigned long long* __restrict__ mask) {
  int wid = blockIdx.x * 4 + (threadIdx.x >> 6);  // 16384 waves total
  int lane = threadIdx.x & 63;
  int b = wid >> 12;         // 4096 waves per batch
  int rb = (wid >> 5) & 127; // row block of 16
  int jb = wid & 31;         // 64-column block
  if (jb < (rb >> 2)) return;  // word-blocks below the row's chunk are never read
  int j = (jb << 6) + lane;
  float4 bj = boxes[(b << 11) + j];
  float areaJ = (bj.z - bj.x) * (bj.w - bj.y);
#pragma unroll
  for (int r = 0; r < 16; ++r) {
    int i = (rb << 4) + r;
    float4 bi = boxes[(b << 11) + i];
    float areaI = (bi.z - bi.x) * (bi.w - bi.y);
    float yA = fmaxf(bi.x, bj.x), xA = fmaxf(bi.y, bj.y);
    float yB = fminf(bi.z, bj.z), xB = fminf(bi.w, bj.w);
    float ih = fmaxf(yB - yA, 0.f), iw = fmaxf(xB - xA, 0.f);
    float inter = ih * iw;
    float uni = areaI + areaJ - inter;
    float iou = inter / (uni + 1e-8f);
    bool pred = (iou > THR_) && (j > i);
    unsigned long long bits = __ballot(pred);
    if (lane == 0) mask[((size_t)((b << 11) + i) << 5) + jb] = bits;
  }
}

// ---- K7: greedy NMS, single wave, barrier-light ----
// Register-prefetch next 16 KB chunk (coalesced dwordx2) while scanning/folding
// the current one from LDS. Scan is uniform (SGPR chain); fold is lane-parallel
// (2 lanes per word x 32 rows, shfl_xor combine, rem in registers) and
// triangular (words > c only; earlier words are dead).
__global__ void __launch_bounds__(64) nms_kernel(const unsigned long long* __restrict__ mask,
                                                 const float4* __restrict__ boxes,
                                                 float4* __restrict__ out) {
  int b = blockIdx.x;
  int lane = threadIdx.x;  // 64 threads = 1 wave
  __shared__ unsigned long long rows[64][33];  // pad 33: scan column read = 4-way not 64-way
  __shared__ unsigned long long keptm[32];
  __shared__ int pre[32];
  __shared__ short sel[P_];
  if (lane < 32) keptm[lane] = 0ull;
  for (int r = lane; r < P_; r += 64) sel[r] = -1;
  int w = lane & 31, half = lane >> 5;
  const unsigned long long* mbase = mask + (((size_t)(b << 11)) << 5);
  unsigned long long r0[32];
  // stage chunk 0 (all words)
#pragma unroll
  for (int j = 0; j < 32; ++j) r0[j] = mbase[j * 64 + lane];
#pragma unroll
  for (int j = 0; j < 32; ++j) rows[2 * j + half][w] = r0[j];
  __syncthreads();
  unsigned long long rem = 0ull;  // lane owns word w (two copies, halves in sync)
  int cnt = 0;
  for (int c = 0; c < 32; ++c) {
    // prefetch chunk c+1, words > c only (triangular)
    bool pf = (c < 31) && (w > c);
    if (pf) {
      const unsigned long long* srcN = mbase + (((size_t)(c + 1)) << 11);
#pragma unroll
      for (int j = 0; j < 32; ++j) r0[j] = srcN[j * 64 + lane];
    }
    // --- scan chunk c (uniform serial, 64 steps) ---
    unsigned long long rin = rows[lane][c];          // row (64c+lane), word c
    unsigned long long cur = readlane64(rem, c);     // suppressed bits for this chunk
    unsigned long long kept = 0ull;
#pragma unroll
    for (int k2 = 0; k2 < 64; ++k2) {
      unsigned long long rk = readlane64(rin, k2);
      unsigned long long alive = ((cur >> k2) & 1ull) ^ 1ull;
      cur |= rk & (0ull - alive);
      kept |= alive << k2;
    }
    if (lane == 0) keptm[c] = kept;
    cnt += (int)__popcll(kept);
    if (cnt >= P_) break;  // later chunks cannot affect first 1000 kept
    // --- fold kept rows into rem (lane-parallel, words > c only) ---
    if (w > c) {
      unsigned long long acc = 0ull;
#pragma unroll
      for (int k2 = 0; k2 < 32; ++k2) {
        int row = half * 32 + k2;
        acc |= rows[row][w] & (0ull - ((kept >> row) & 1ull));
      }
      acc |= __shfl_xor(acc, 32, 64);
      rem |= acc;
    }
    // --- commit prefetched chunk c+1 to LDS ---
    if (pf) {
#pragma unroll
      for (int j = 0; j < 32; ++j) rows[2 * j + half][w] = r0[j];
    }
    __syncthreads();
  }
  __syncthreads();
  if (lane == 0) {
    int run = 0;
    for (int c = 0; c < 32; ++c) { pre[c] = run; run += (int)__popcll(keptm[c]); }
  }
  __syncthreads();
  for (int i = lane; i < K_; i += 64) {
    int c = i >> 6, k2 = i & 63;
    unsigned long long km = keptm[c];
    if ((km >> k2) & 1ull) {
      int rank = pre[c] + (int)__popcll(km & ((1ull << k2) - 1ull));
      if (rank < P_) sel[rank] = (short)i;
    }
  }
  __syncthreads();
  for (int r = lane; r < P_; r += 64) {
    int i = sel[r];
    float4 v = make_float4(0.f, 0.f, 0.f, 0.f);
    if (i >= 0) v = boxes[(b << 11) + i];
    out[b * P_ + r] = v;
  }
}

extern "C" void kernel_launch(void* const* d_in, const int* in_sizes, int n_in,
                              void* d_out, int out_size, void* d_ws, size_t ws_size,
                              hipStream_t stream) {
  const float4* probs4 = (const float4*)d_in[0];     // (B,N,2) viewed as float4
  const float4* bbox   = (const float4*)d_in[1];     // (B,N,4)
  const float4* anch   = (const float4*)d_in[2];     // (B,N,4)
  char* ws = (char*)d_ws;
  unsigned* hist = (unsigned*)(ws + OFF_HIST);
  unsigned* meta = (unsigned*)(ws + OFF_META);
  unsigned* coarse = (unsigned*)(ws + OFF_COARSE);
  uint2* cand = (uint2*)(ws + OFF_CAND);
  float4* boxes = (float4*)(ws + OFF_BOX);
  unsigned long long* mask = (unsigned long long*)(ws + OFF_MASK);
  unsigned* partial = (unsigned*)(ws + OFF_MASK);  // aliases mask (consumed before mask written)
  float4* out = (float4*)d_out;

  hipMemsetAsync(ws, 0, OFF_COARSE, stream);  // zero hist + meta

  hist_kernel<<<dim3(62, B_), 1024, 0, stream>>>(probs4, hist);           // 62*8192 >= 500k f4
  coarse_kernel<<<dim3(256, B_), 64, 0, stream>>>(hist, coarse);
  select_kernel<<<B_, 256, 0, stream>>>(hist, coarse, meta);
  compact_kernel<<<dim3(245, B_), 256, 0, stream>>>(probs4, meta, cand);  // 245*2048 >= 500k f4
  rank_kernel<<<dim3(CAP_ / 256, NCH_, B_), 256, 0, stream>>>(cand, meta, partial);
  scatter_kernel<<<dim3(CAP_ / 256, B_), 256, 0, stream>>>(cand, meta, partial, bbox, anch, boxes);
  mask_kernel<<<(B_ * 128 * 32) / 4, 256, 0, stream>>>(boxes, mask);
  nms_kernel<<<B_, 64, 0, stream>>>(mask, boxes, out);
}

// Round 2
// 218.296 us; speedup vs baseline: 1.4171x; 1.1685x over previous
//
#include <hip/hip_runtime.h>

#define B_ 4
#define N_ 1000000
#define K_ 2048
#define P_ 1000
#define CAP_ 8192
#define THR_ 0.7f
#define NF4_ 500000     // float4 count per batch of (N,2) float array
#define META_STRIDE 32  // u32 per batch -> 128 B: counters on separate cache lines
#define TILE_ 512       // rank tile (candidates per tile-chunk)
#define NCH_ (CAP_ / TILE_)  // 16 tile chunks max

// ---- workspace layout (bytes) ----
// hist   : B * 65536 * 4 = 1,048,576
// meta   : 1024  (per batch at b*META_STRIDE: [0]=threshold bucket, [1]=candidate count)
// coarse : B * 256 * 4 = 4,096
// cand   : B * CAP * 8   = 262,144   (uint2: key, idx)
// topidx : B * K * 4     = 32,768    (unused after scatter fusion; layout kept)
// boxes  : B * K * 16    = 131,072
// mask   : B * K * 32 * 8 = 2,097,152
//   NOTE: partial-rank array (B * NCH_ * CAP_ * 4 = 2,097,152) ALIASES mask:
//   rank_kernel writes it, scatter_kernel consumes it, THEN mask_kernel overwrites.
#define OFF_HIST 0
#define OFF_META 1048576
#define OFF_COARSE (OFF_META + 1024)
#define OFF_CAND (OFF_COARSE + 4096)
#define OFF_TOPI (OFF_CAND + 262144)
#define OFF_BOX  (OFF_TOPI + 32768)
#define OFF_MASK (OFF_BOX + 131072)

__device__ __forceinline__ unsigned fkey(float f) {
  unsigned u = __float_as_uint(f);
  return (u & 0x80000000u) ? ~u : (u | 0x80000000u);
}

__device__ __forceinline__ unsigned long long readlane64(unsigned long long v, int l) {
  unsigned lo = (unsigned)__builtin_amdgcn_readlane((int)(unsigned)(v & 0xffffffffull), l);
  unsigned hi = (unsigned)__builtin_amdgcn_readlane((int)(unsigned)(v >> 32), l);
  return ((unsigned long long)hi << 32) | (unsigned long long)lo;
}

#define PIN16(k) asm volatile("" : "+v"(k[0]), "+v"(k[1]), "+v"(k[2]), "+v"(k[3]), \
                                   "+v"(k[4]), "+v"(k[5]), "+v"(k[6]), "+v"(k[7]), \
                                   "+v"(k[8]), "+v"(k[9]), "+v"(k[10]), "+v"(k[11]), \
                                   "+v"(k[12]), "+v"(k[13]), "+v"(k[14]), "+v"(k[15]))

// ---- K1: LDS-privatized histogram of top-16 bits of monotonic key ----
__global__ void __launch_bounds__(1024) hist_kernel(const float4* __restrict__ probs4,
                                                    unsigned* __restrict__ hist) {
  int b = blockIdx.y;
  __shared__ unsigned h[32768];
  for (int i = threadIdx.x; i < 32768; i += 1024) h[i] = 0u;
  __syncthreads();
  const float4* p4 = probs4 + (size_t)b * NF4_;
  int base = blockIdx.x * 8192;
  float4 v[8];
#pragma unroll
  for (int c = 0; c < 8; ++c) {
    int i4 = base + c * 1024 + threadIdx.x;
    v[c] = (i4 < NF4_) ? p4[i4] : make_float4(0.f, 0.f, 0.f, 0.f);
  }
  unsigned k[16];
#pragma unroll
  for (int c = 0; c < 8; ++c) { k[2 * c] = fkey(v[c].y) >> 16; k[2 * c + 1] = fkey(v[c].w) >> 16; }
  PIN16(k);
#pragma unroll
  for (int c = 0; c < 8; ++c) {
    int i4 = base + c * 1024 + threadIdx.x;
    if (i4 < NF4_) {
      unsigned b0 = k[2 * c], b1 = k[2 * c + 1];
      atomicAdd(&h[b0 >> 1], 1u << ((b0 & 1u) << 4));
      atomicAdd(&h[b1 >> 1], 1u << ((b1 & 1u) << 4));
    }
  }
  __syncthreads();
  unsigned* g = hist + ((size_t)b << 16);
  for (int w = threadIdx.x; w < 32768; w += 1024) {
    unsigned x = h[w];
    if (x) {
      unsigned c0 = x & 0xFFFFu, c1 = x >> 16;
      if (c0) atomicAdd(&g[2 * w], c0);
      if (c1) atomicAdd(&g[2 * w + 1], c1);
    }
  }
}

// ---- K2a: coarse sums — one wave per 256-bucket group, coalesced + shfl-reduce ----
__global__ void __launch_bounds__(64) coarse_kernel(const unsigned* __restrict__ hist,
                                                    unsigned* __restrict__ coarse) {
  int b = blockIdx.y, g = blockIdx.x, lane = threadIdx.x;
  const uint4* h4 = (const uint4*)(hist + (((size_t)b) << 16) + ((size_t)g << 8));
  uint4 v = h4[lane];
  unsigned s = v.x + v.y + v.z + v.w;
#pragma unroll
  for (int off = 32; off >= 1; off >>= 1) s += __shfl_xor(s, off, 64);
  if (lane == 0) coarse[b * 256 + g] = s;
}

// ---- K2b: find smallest bucket cb with count(bucket >= cb) >= K ----
__global__ void select_kernel(const unsigned* __restrict__ hist, const unsigned* __restrict__ coarse,
                              unsigned* __restrict__ meta) {
  int b = blockIdx.x, t = threadIdx.x;  // 256 threads
  __shared__ unsigned suf[256];
  __shared__ int tc_s;
  __shared__ unsigned above_s;
  const unsigned* g = hist + ((size_t)b << 16);
  suf[t] = coarse[b * 256 + t];
  __syncthreads();
  for (int off = 1; off < 256; off <<= 1) {
    unsigned add = (t + off < 256) ? suf[t + off] : 0u;
    __syncthreads();
    suf[t] += add;
    __syncthreads();
  }
  unsigned nxt = (t < 255) ? suf[t + 1] : 0u;
  if (suf[t] >= K_ && (t == 255 || nxt < K_)) { tc_s = t; above_s = nxt; }
  __syncthreads();
  int tc = tc_s;
  unsigned above = above_s;
  unsigned bs = g[tc * 256 + t];
  __syncthreads();
  suf[t] = bs;
  __syncthreads();
  for (int off = 1; off < 256; off <<= 1) {
    unsigned add = (t + off < 256) ? suf[t + off] : 0u;
    __syncthreads();
    suf[t] += add;
    __syncthreads();
  }
  unsigned nxt2 = (t < 255) ? suf[t + 1] : 0u;
  if (above + suf[t] >= K_ && (t == 255 || above + nxt2 < K_))
    meta[b * META_STRIDE + 0] = (unsigned)(tc * 256 + t);
}

// ---- K3: compact candidates (bucket >= cb), LDS-buffered, 1 global atomic/block ----
__global__ void __launch_bounds__(256) compact_kernel(const float4* __restrict__ probs4,
                                                      unsigned* __restrict__ meta,
                                                      uint2* __restrict__ cand) {
  int b = blockIdx.y;
  __shared__ unsigned lcnt, gbase_s;
  __shared__ uint2 buf[4096];
  if (threadIdx.x == 0) lcnt = 0u;
  __syncthreads();
  unsigned cb = meta[b * META_STRIDE + 0];
  const float4* p4 = probs4 + (size_t)b * NF4_;
  int base = blockIdx.x * 2048;
  int lane = threadIdx.x & 63;
  float4 v[8];
#pragma unroll
  for (int c = 0; c < 8; ++c) {
    int i4 = base + c * 256 + threadIdx.x;
    v[c] = (i4 < NF4_) ? p4[i4] : make_float4(0.f, 0.f, 0.f, 0.f);
  }
  unsigned k[16];
#pragma unroll
  for (int c = 0; c < 8; ++c) { k[2 * c] = fkey(v[c].y); k[2 * c + 1] = fkey(v[c].w); }
  PIN16(k);
#pragma unroll
  for (int c = 0; c < 8; ++c) {
#pragma unroll
    for (int s = 0; s < 2; ++s) {
      int i4 = base + c * 256 + threadIdx.x;
      unsigned key = k[2 * c + s];
      bool pass = (i4 < NF4_) && ((key >> 16) >= cb);
      unsigned long long m = __ballot(pass);
      if (m) {
        int leader = __ffsll(m) - 1;
        unsigned wbase = 0;
        if (lane == leader) wbase = atomicAdd(&lcnt, (unsigned)__popcll(m));
        wbase = __shfl(wbase, leader, 64);
        if (pass) {
          unsigned pos = wbase + (unsigned)__popcll(m & ((1ull << lane) - 1ull));
          buf[pos] = make_uint2(key, (unsigned)(2 * i4 + s));
        }
      }
    }
  }
  __syncthreads();
  unsigned cnt = lcnt;
  if (threadIdx.x == 0) gbase_s = atomicAdd(&meta[b * META_STRIDE + 1], cnt);
  __syncthreads();
  unsigned gbase = gbase_s;
  for (unsigned i = threadIdx.x; i < cnt; i += 256) {
    unsigned pos = gbase + i;
    if (pos < CAP_) cand[(size_t)b * CAP_ + pos] = buf[i];
  }
}

// ---- K4: exact rank by counting, 2D-split (ci-chunk x tile-chunk) for occupancy ----
__global__ void __launch_bounds__(256) rank_kernel(const uint2* __restrict__ cand,
                                                   const unsigned* __restrict__ meta,
                                                   unsigned* __restrict__ partial) {
  int b = blockIdx.z;
  unsigned M = meta[b * META_STRIDE + 1];
  if (M > CAP_) M = CAP_;
  unsigned tb = blockIdx.y * TILE_;
  if (tb >= M) return;
  if ((unsigned)(blockIdx.x * 256) >= M) return;
  __shared__ __align__(16) uint2 tile[TILE_];
  unsigned n = M - tb;
  if (n > TILE_) n = TILE_;
  for (unsigned t = threadIdx.x; t < n; t += 256) tile[t] = cand[(size_t)b * CAP_ + tb + t];
  int ci = blockIdx.x * 256 + threadIdx.x;
  bool act = ci < (int)M;
  uint2 me = make_uint2(0u, 0u);
  if (act) me = cand[(size_t)b * CAP_ + ci];
  unsigned long long my = ((unsigned long long)me.x << 32) | (unsigned long long)(unsigned)(~me.y);
  __syncthreads();
  if (act) {
    unsigned rank = 0;
    unsigned n2 = n >> 1;
    const uint4* t4 = (const uint4*)tile;
    for (unsigned j = 0; j < n2; ++j) {
      uint4 v = t4[j];
      unsigned long long c0 = ((unsigned long long)v.x << 32) | (unsigned long long)(unsigned)(~v.y);
      unsigned long long c1 = ((unsigned long long)v.z << 32) | (unsigned long long)(unsigned)(~v.w);
      rank += (unsigned)(c0 > my) + (unsigned)(c1 > my);
    }
    if (n & 1) {
      uint2 v = tile[n - 1];
      unsigned long long c0 = ((unsigned long long)v.x << 32) | (unsigned long long)(unsigned)(~v.y);
      rank += (unsigned)(c0 > my);
    }
    partial[((size_t)b * NCH_ + blockIdx.y) * CAP_ + ci] = rank;
  }
}

// ---- K5: sum partial ranks, gather anchors/deltas, decode boxes, clip (fused) ----
__global__ void __launch_bounds__(256) scatter_kernel(const uint2* __restrict__ cand,
                                                      const unsigned* __restrict__ meta,
                                                      const unsigned* __restrict__ partial,
                                                      const float4* __restrict__ bbox,
                                                      const float4* __restrict__ anch,
                                                      float4* __restrict__ boxes) {
  int b = blockIdx.y;
  unsigned M = meta[b * META_STRIDE + 1];
  if (M > CAP_) M = CAP_;
  unsigned ci = blockIdx.x * 256 + threadIdx.x;
  if (ci >= M) return;
  unsigned nch = (M + TILE_ - 1) / TILE_;
  const unsigned* pp = partial + (size_t)b * NCH_ * CAP_ + ci;
  unsigned rank = 0;
  for (unsigned c = 0; c < nch; ++c) rank += pp[(size_t)c * CAP_];
  if (rank >= K_) return;
  unsigned idx = cand[(size_t)b * CAP_ + ci].y;
  size_t base = (size_t)b * N_ + idx;
  float4 a = anch[base];
  float4 d = bbox[base];
  float d0 = d.x * 0.1f, d1 = d.y * 0.1f, d2 = d.z * 0.2f, d3 = d.w * 0.2f;
  float h = a.z - a.x, w = a.w - a.y;
  float cy = (a.x + 0.5f * h) + d0 * h;
  float cx = (a.y + 0.5f * w) + d1 * w;
  float h2 = h * expf(d2);
  float w2 = w * expf(d3);
  float y1 = cy - 0.5f * h2, x1 = cx - 0.5f * w2;
  float y2 = cy + 0.5f * h2, x2 = cx + 0.5f * w2;
  y1 = fminf(fmaxf(y1, 0.f), 1.f);
  x1 = fminf(fmaxf(x1, 0.f), 1.f);
  y2 = fminf(fmaxf(y2, 0.f), 1.f);
  x2 = fminf(fmaxf(x2, 0.f), 1.f);
  boxes[(b << 11) + rank] = make_float4(y1, x1, y2, x2);
}

// ---- K6: IoU suppression bitmask (upper-triangular word-blocks only) ----
__global__ void mask_kernel(const float4* __restrict__ boxes, unsigned long long* __restrict__ mask) {
  int wid = blockIdx.x * 4 + (threadIdx.x >> 6);  // 16384 waves total
  int lane = threadIdx.x & 63;
  int b = wid >> 12;         // 4096 waves per batch
  int rb = (wid >> 5) & 127; // row block of 16
  int jb = wid & 31;         // 64-column block
  if (jb < (rb >> 2)) return;  // word-blocks below the row's chunk are never read
  int j = (jb << 6) + lane;
  float4 bj = boxes[(b << 11) + j];
  float areaJ = (bj.z - bj.x) * (bj.w - bj.y);
#pragma unroll
  for (int r = 0; r < 16; ++r) {
    int i = (rb << 4) + r;
    float4 bi = boxes[(b << 11) + i];
    float areaI = (bi.z - bi.x) * (bi.w - bi.y);
    float yA = fmaxf(bi.x, bj.x), xA = fmaxf(bi.y, bj.y);
    float yB = fminf(bi.z, bj.z), xB = fminf(bi.w, bj.w);
    float ih = fmaxf(yB - yA, 0.f), iw = fmaxf(xB - xA, 0.f);
    float inter = ih * iw;
    float uni = areaI + areaJ - inter;
    float iou = inter / (uni + 1e-8f);
    bool pred = (iou > THR_) && (j > i);
    unsigned long long bits = __ballot(pred);
    if (lane == 0) mask[((size_t)((b << 11) + i) << 5) + jb] = bits;
  }
}

// ---- K7: greedy NMS, 4 waves, sparse scan ----
// Scan: suppression is sparse for random boxes, so instead of a 64-step serial
// bit-chain, ballot the rows whose in-chunk word is nonzero (typically 0-2) and
// process only those, in order. kept = ~cur_final is exact because mask bits are
// strictly upper-triangular (j > i), so bit k is final once rows < k processed.
// Fold/prefetch/commit: spread over 4 waves (8 rows/thread), rem lives in LDS
// (wave-half shfl-combine, then u32 atomicOr). Double-buffered rows: 2 barriers/chunk.
__global__ void __launch_bounds__(256) nms_kernel(const unsigned long long* __restrict__ mask,
                                                  const float4* __restrict__ boxes,
                                                  float4* __restrict__ out) {
  int b = blockIdx.x;
  int t = threadIdx.x;
  int wid = t >> 6, lane = t & 63;
  int w = lane & 31, half = lane >> 5;
  __shared__ unsigned long long rows[2][64][33];  // pad 33: scan column read not 64-way
  __shared__ unsigned long long remS[32];
  __shared__ unsigned long long keptm[32];
  __shared__ int pre[32];
  __shared__ short sel[P_];
  __shared__ int stopF;
  if (t < 32) { remS[t] = 0ull; keptm[t] = 0ull; }
  if (t == 0) stopF = 0;
  for (int r = t; r < P_; r += 256) sel[r] = -1;
  const unsigned long long* mbase = mask + (((size_t)(b << 11)) << 5);
  unsigned long long r0[8];
  int rowb = 2 * wid + half;  // thread owns rows 8*j + rowb, word w
  // stage chunk 0 (all words) into buffer 0
#pragma unroll
  for (int j = 0; j < 8; ++j) r0[j] = mbase[j * 256 + t];
#pragma unroll
  for (int j = 0; j < 8; ++j) rows[0][8 * j + rowb][w] = r0[j];
  __syncthreads();
  int cb = 0;
  int cnt = 0;
  for (int c = 0; c < 32; ++c) {
    // prefetch chunk c+1, words > c only (triangular)
    bool pf = (c < 31) && (w > c);
    if (pf) {
      const unsigned long long* srcN = mbase + (((size_t)(c + 1)) << 11);
#pragma unroll
      for (int j = 0; j < 8; ++j) r0[j] = srcN[j * 256 + t];
    }
    // --- sparse scan of chunk c (wave 0) ---
    if (wid == 0) {
      unsigned long long rin = rows[cb][lane][c];  // row (64c+lane), word c
      unsigned long long cur = remS[c];            // suppressed bits entering this chunk
      unsigned long long bm = __ballot(rin != 0ull);
      while (bm) {
        int k2 = __ffsll((long long)bm) - 1;
        bm &= bm - 1;
        if (!((cur >> k2) & 1ull)) cur |= readlane64(rin, k2);
      }
      unsigned long long kept = ~cur;
      cnt += (int)__popcll(kept);
      if (lane == 0) {
        keptm[c] = kept;
        if (cnt >= P_) stopF = 1;  // later chunks cannot affect first 1000 kept
      }
    }
    __syncthreads();
    if (stopF) break;
    // --- fold kept rows into remS (words > c), 8 rows/thread ---
    if (w > c) {
      unsigned long long kept = keptm[c];
      unsigned long long acc = 0ull;
#pragma unroll
      for (int j = 0; j < 8; ++j) {
        int row = 8 * j + rowb;
        acc |= rows[cb][row][w] & (0ull - ((kept >> row) & 1ull));
      }
      acc |= __shfl_xor(acc, 32, 64);
      if (half == 0) {
        unsigned lo = (unsigned)acc, hi = (unsigned)(acc >> 32);
        unsigned* rp = (unsigned*)&remS[w];
        if (lo) atomicOr(rp, lo);
        if (hi) atomicOr(rp + 1, hi);
      }
    }
    // --- commit prefetched chunk c+1 into other buffer ---
    if (pf) {
#pragma unroll
      for (int j = 0; j < 8; ++j) rows[cb ^ 1][8 * j + rowb][w] = r0[j];
    }
    __syncthreads();
    cb ^= 1;
  }
  __syncthreads();
  if (t == 0) {
    int run = 0;
    for (int c = 0; c < 32; ++c) { pre[c] = run; run += (int)__popcll(keptm[c]); }
  }
  __syncthreads();
  for (int i = t; i < K_; i += 256) {
    int c = i >> 6, k2 = i & 63;
    unsigned long long km = keptm[c];
    if ((km >> k2) & 1ull) {
      int rank = pre[c] + (int)__popcll(km & ((1ull << k2) - 1ull));
      if (rank < P_) sel[rank] = (short)i;
    }
  }
  __syncthreads();
  for (int r = t; r < P_; r += 256) {
    int i = sel[r];
    float4 v = make_float4(0.f, 0.f, 0.f, 0.f);
    if (i >= 0) v = boxes[(b << 11) + i];
    out[b * P_ + r] = v;
  }
}

extern "C" void kernel_launch(void* const* d_in, const int* in_sizes, int n_in,
                              void* d_out, int out_size, void* d_ws, size_t ws_size,
                              hipStream_t stream) {
  const float4* probs4 = (const float4*)d_in[0];     // (B,N,2) viewed as float4
  const float4* bbox   = (const float4*)d_in[1];     // (B,N,4)
  const float4* anch   = (const float4*)d_in[2];     // (B,N,4)
  char* ws = (char*)d_ws;
  unsigned* hist = (unsigned*)(ws + OFF_HIST);
  unsigned* meta = (unsigned*)(ws + OFF_META);
  unsigned* coarse = (unsigned*)(ws + OFF_COARSE);
  uint2* cand = (uint2*)(ws + OFF_CAND);
  float4* boxes = (float4*)(ws + OFF_BOX);
  unsigned long long* mask = (unsigned long long*)(ws + OFF_MASK);
  unsigned* partial = (unsigned*)(ws + OFF_MASK);  // aliases mask (consumed before mask written)
  float4* out = (float4*)d_out;

  hipMemsetAsync(ws, 0, OFF_COARSE, stream);  // zero hist + meta

  hist_kernel<<<dim3(62, B_), 1024, 0, stream>>>(probs4, hist);           // 62*8192 >= 500k f4
  coarse_kernel<<<dim3(256, B_), 64, 0, stream>>>(hist, coarse);
  select_kernel<<<B_, 256, 0, stream>>>(hist, coarse, meta);
  compact_kernel<<<dim3(245, B_), 256, 0, stream>>>(probs4, meta, cand);  // 245*2048 >= 500k f4
  rank_kernel<<<dim3(CAP_ / 256, NCH_, B_), 256, 0, stream>>>(cand, meta, partial);
  scatter_kernel<<<dim3(CAP_ / 256, B_), 256, 0, stream>>>(cand, meta, partial, bbox, anch, boxes);
  mask_kernel<<<(B_ * 128 * 32) / 4, 256, 0, stream>>>(boxes, mask);
  nms_kernel<<<B_, 256, 0, stream>>>(mask, boxes, out);
}